// Round 2
// baseline (239.934 us; speedup 1.0000x reference)
//
#include <hip/hip_runtime.h>

// ---------------------------------------------------------------------------
// GaussianDiffusionTrainer forward:
//   x_t[b,c,h,w] = x0[b,c,h,w] * P[t_b-1] + (h==w ? normal[b,c,h,w] * C[t_b-1] : 0)
// Shapes: (8192, 3, 32, 32) fp32, timesteps int32 in [1,1000].
// P, C are a 1000-step serial fp32 scan over a linear beta schedule —
// computed at COMPILE TIME (constexpr) and baked into __constant__ memory.
// ---------------------------------------------------------------------------

constexpr int T_STEPS = 1000;
constexpr int BATCH   = 8192;
constexpr int N_ELEM  = BATCH * 3 * 32 * 32;   // 25,165,824
constexpr int NF4     = N_ELEM / 4;            // 6,291,456 float4s

struct Tables { float P[T_STEPS]; float C[T_STEPS]; };

// constexpr double sqrt: normalize into [0.25,1) by pow2 scaling, then
// Newton iterations; scale is a power of two so the rescale is exact.
constexpr double csqrt_d(double x) {
    if (x <= 0.0) return 0.0;
    double scale = 1.0;
    while (x < 0.25) { x *= 4.0;  scale *= 0.5; }
    while (x >= 1.0) { x *= 0.25; scale *= 2.0; }
    double g = 0.5 * (x + 1.0);
    for (int i = 0; i < 40; ++i) {
        double ng = 0.5 * (g + x / g);
        if (ng == g) break;
        g = ng;
    }
    return g * scale;
}

// Serial fp32 scan exactly mirroring the reference:
//   betas = linspace(1e-4, 0.02, 1001)[k], k = 0..999 used (idx = t-1 <= 999)
//   ac    = cumprod(1 - beta);  s = sqrt(ac);  P = cumprod(s)
//   C scan: c = c*s_k + beta_k^2
constexpr Tables make_tables() {
    Tables t{};
    const float beta1 = 1e-4f;
    const float betaT = 0.02f;
    const float delta = (betaT - beta1) / 1000.0f;   // (stop-start)/(num-1), f32
    float ac = 1.0f, P = 1.0f, c = 0.0f;
    for (int k = 0; k < T_STEPS; ++k) {
        float beta = beta1 + (float)k * delta;
        ac = ac * (1.0f - beta);
        float s = (float)csqrt_d((double)ac);
        P = P * s;
        c = c * s + beta * beta;
        t.P[k] = P;
        t.C[k] = c;
    }
    return t;
}

__device__ __constant__ Tables d_tbl = make_tables();

__global__ __launch_bounds__(256) void gaussian_diffusion_kernel(
    const float* __restrict__ x0,
    const float* __restrict__ nrm,
    const int*   __restrict__ tsteps,
    float*       __restrict__ out)
{
    int f = blockIdx.x * 256 + threadIdx.x;      // float4 index
    if (f >= NF4) return;
    int e   = f << 2;                            // element index (multiple of 4)
    int b   = e / 3072;                          // image = 3*32*32 = 3072 elems
    int rem = e - b * 3072;
    int p   = rem & 1023;                        // position within channel
    int h   = p >> 5;
    int w0  = p & 31;                            // multiple of 4

    int   t  = tsteps[b] - 1;                    // in [0, 999]
    float Pt = d_tbl.P[t];
    float Ct = d_tbl.C[t];

    const float4 x = reinterpret_cast<const float4*>(x0)[f];

    // diagonal element (w == h) falls in this float4 iff d = h - w0 in [0,4)
    int   d  = h - w0;
    float nv = 0.0f;
    if ((unsigned)d < 4u) nv = nrm[e + d] * Ct;

    float4 r;
    r.x = x.x * Pt + (d == 0 ? nv : 0.0f);
    r.y = x.y * Pt + (d == 1 ? nv : 0.0f);
    r.z = x.z * Pt + (d == 2 ? nv : 0.0f);
    r.w = x.w * Pt + (d == 3 ? nv : 0.0f);

    reinterpret_cast<float4*>(out)[f] = r;
}

extern "C" void kernel_launch(void* const* d_in, const int* in_sizes, int n_in,
                              void* d_out, int out_size, void* d_ws, size_t ws_size,
                              hipStream_t stream) {
    const float* x0     = (const float*)d_in[0];
    const float* nrm    = (const float*)d_in[1];
    const int*   tsteps = (const int*)d_in[2];
    float*       out    = (float*)d_out;

    const int blocks = NF4 / 256;                // 24576
    gaussian_diffusion_kernel<<<blocks, 256, 0, stream>>>(x0, nrm, tsteps, out);
}